// Round 13
// baseline (71.943 us; speedup 1.0000x reference)
//
#include <hip/hip_runtime.h>
#include <hip/hip_bf16.h>

// Bundle-adjustment residual.
// R13: remove the pose gathers from the TA/L1 request path.
// Cost model (fits R3/R12): divergent gathers are served at ~1 lane-request
// per cycle per CU. R12: 12 gather instrs/thread -> 98K req/CU -> 41us
// (measured 41.5). Pose = 8 of those 12. This round:
//  - pose table pre-normalized + repacked to STRIDE-9 floats (36B/pose,
//    gcd(9,32)=1 -> divergent scalar LDS reads spread over all 32 banks),
//    staged into 144KB STATIC LDS (R11 precedent: >64KB static compiles)
//    via coalesced linear float4 copy; grid=256 -> one staging per CU.
//  - patch = 1 sc0 gather/obs from packed patch4 ws table (R12-proven).
//  - compute in two R12-proven passes of 4 obs (issue gathers + NT streams,
//    one vmcnt(0)+sched_barrier fence, compute, NT store) -> no 8-deep
//    register batching -> no spills (R8/R9/R11 lesson).
//  - all fp32 (R10 lesson: atan2 branch cut forbids input quantization).

#define NPOSES   4096
#define NPATCHES 262144
#define POSE_STRIDE 9                          // floats per pose (7 + 2 pad)
#define POSE_LDS_FLOATS (NPOSES * POSE_STRIDE) // 36864 floats = 144 KB
#define POSE_LDS_VEC4   (POSE_LDS_FLOATS / 4)  // 9216 float4

typedef float fvec4 __attribute__((ext_vector_type(4)));
typedef int   ivec4 __attribute__((ext_vector_type(4)));

// One pack dispatch: every thread packs a patch; threads < NPOSES also pack
// a pose (normalized, stride-9 layout).
__global__ __launch_bounds__(256) void pack_tables_kernel(
    const float* __restrict__ poses,         // [4096,7]
    const float* __restrict__ patch_coords,  // [NPATCHES,2]
    const float* __restrict__ elev,          // [NPATCHES,1]
    float*       __restrict__ pose9,         // [NPOSES*9]
    fvec4*       __restrict__ patch4,        // [NPATCHES]
    int n)
{
    int i = blockIdx.x * blockDim.x + threadIdx.x;
    if (i >= n) return;
    float2 pc = *reinterpret_cast<const float2*>(patch_coords + (size_t)i * 2);
    patch4[i] = (fvec4){pc.x, pc.y, elev[i], 0.0f};

    if (i < NPOSES) {
        const float* p = poses + (size_t)i * 7;
        float tx = p[0], ty = p[1], tz = p[2];
        float qx = p[3], qy = p[4], qz = p[5], qw = p[6];
        float inv = rsqrtf(qx*qx + qy*qy + qz*qz + qw*qw);
        float* d = pose9 + (size_t)i * POSE_STRIDE;
        d[0] = tx;      d[1] = ty;      d[2] = tz;
        d[3] = qx*inv;  d[4] = qy*inv;  d[5] = qz*inv;  d[6] = qw*inv;
        d[7] = 0.0f;    d[8] = 0.0f;
    }
}

__device__ __forceinline__ fvec4 load_sc0(const fvec4* addr) {
    fvec4 v;
    asm volatile("global_load_dwordx4 %0, %1, off sc0" : "=v"(v) : "v"(addr));
    return v;
}

__global__ __launch_bounds__(1024) void ba_main_kernel(
    const float* __restrict__ pose9,    // [NPOSES*9] packed, normalized
    const fvec4* __restrict__ patch4,   // [NPATCHES] (x,y,elev,0)
    const int*   __restrict__ poses_idx,
    const int*   __restrict__ patch_idx,
    const float* __restrict__ target,   // [NOBS,3]
    const float* __restrict__ weights,  // [NOBS,1]
    float*       __restrict__ out,      // [NOBS,3]
    int n8)                             // NOBS/8
{
    __shared__ float lds[POSE_LDS_FLOATS];   // 144 KB static -> 1 block/CU
    int tid = threadIdx.x;

    // Coalesced linear staging: 9216 float4 / 1024 threads = 9 each.
    {
        const fvec4* src = reinterpret_cast<const fvec4*>(pose9);
        fvec4* dst = reinterpret_cast<fvec4*>(lds);
#pragma unroll
        for (int k = 0; k < POSE_LDS_VEC4 / 1024; ++k)
            dst[tid + k * 1024] = src[tid + k * 1024];
    }
    __syncthreads();

    int i8 = blockIdx.x * blockDim.x + tid;
    if (i8 >= n8) return;

    const ivec4* pi4 = reinterpret_cast<const ivec4*>(poses_idx) + (size_t)i8 * 2;
    const ivec4* qi4 = reinterpret_cast<const ivec4*>(patch_idx) + (size_t)i8 * 2;
    const fvec4* w4p = reinterpret_cast<const fvec4*>(weights) + (size_t)i8 * 2;
    const fvec4* tg4 = reinterpret_cast<const fvec4*>(target) + (size_t)i8 * 6;
    fvec4*       o4  = reinterpret_cast<fvec4*>(out) + (size_t)i8 * 6;

#pragma unroll
    for (int g = 0; g < 2; ++g) {
        // Indices for this pass (gather addresses depend on them).
        ivec4 pidx = __builtin_nontemporal_load(pi4 + g);
        ivec4 qidx = __builtin_nontemporal_load(qi4 + g);

        // Issue the 4 patch gathers back-to-back, L1-bypassed (sc0).
        fvec4 pp0 = load_sc0(patch4 + qidx.x);
        fvec4 pp1 = load_sc0(patch4 + qidx.y);
        fvec4 pp2 = load_sc0(patch4 + qidx.z);
        fvec4 pp3 = load_sc0(patch4 + qidx.w);

        // Streams (NT), in flight with the gathers.
        fvec4 w4 = __builtin_nontemporal_load(w4p + g);
        fvec4 t0 = __builtin_nontemporal_load(tg4 + g * 3 + 0);
        fvec4 t1 = __builtin_nontemporal_load(tg4 + g * 3 + 1);
        fvec4 t2 = __builtin_nontemporal_load(tg4 + g * 3 + 2);

        // Drain VMEM; fence so no consumer hoists above the wait (rule 18).
        asm volatile("s_waitcnt vmcnt(0)" ::: "memory");
        __builtin_amdgcn_sched_barrier(0);

        int   pi[4] = {pidx.x, pidx.y, pidx.z, pidx.w};
        float ww[4] = {w4.x, w4.y, w4.z, w4.w};
        float tg[12] = {t0.x, t0.y, t0.z, t0.w,
                        t1.x, t1.y, t1.z, t1.w,
                        t2.x, t2.y, t2.z, t2.w};
        fvec4 pp[4] = {pp0, pp1, pp2, pp3};

        float res[12];
#pragma unroll
        for (int k = 0; k < 4; ++k) {
            // Pose from LDS: 7 scalar reads at stride-9 rows (banks uniform).
            const float* pl = lds + pi[k] * POSE_STRIDE;
            float tx = pl[0], ty = pl[1], tz = pl[2];
            float qx = pl[3], qy = pl[4], qz = pl[5], qw = pl[6];

            float px = pp[k].x, py = pp[k].y, pz = pp[k].z;

            // uv = cross(qv, pts)
            float ux = qy*pz - qz*py;
            float uy = qz*px - qx*pz;
            float uz = qx*py - qy*px;
            // cross(qv, uv)
            float cx = qy*uz - qz*uy;
            float cy = qz*ux - qx*uz;
            float cz = qx*uy - qy*ux;
            // rotated = pts + 2*(qw*uv + cross(qv,uv)) + t  (q pre-normalized)
            float rx = px + 2.0f*(qw*ux + cx) + tx;
            float ry = py + 2.0f*(qw*uy + cy) + ty;
            float rz = pz + 2.0f*(qw*uz + cz) + tz;

            // cart2polar (matches reference)
            float rho = sqrtf(rx*rx + ry*ry);
            float r   = sqrtf(rho*rho + rz*rz);
            float az  = atan2f(ry, rx);
            float el  = atan2f(rz, rho);

            res[k*3 + 0] = (r  - tg[k*3 + 0]) * ww[k];
            res[k*3 + 1] = (az - tg[k*3 + 1]) * ww[k];
            res[k*3 + 2] = (el - tg[k*3 + 2]) * ww[k];
        }

        __builtin_nontemporal_store((fvec4){res[0], res[1], res[2],  res[3]},  o4 + g*3 + 0);
        __builtin_nontemporal_store((fvec4){res[4], res[5], res[6],  res[7]},  o4 + g*3 + 1);
        __builtin_nontemporal_store((fvec4){res[8], res[9], res[10], res[11]}, o4 + g*3 + 2);
    }
}

// Fallback path: direct global gathers (no ws needed).
__global__ __launch_bounds__(256) void ba_fallback_kernel(
    const float* __restrict__ poses, const float* __restrict__ patch_coords,
    const float* __restrict__ elev, const int* __restrict__ poses_idx,
    const int* __restrict__ patch_idx, const float* __restrict__ target,
    const float* __restrict__ weights, float* __restrict__ out, int n)
{
    int i = blockIdx.x * blockDim.x + threadIdx.x;
    if (i >= n) return;
    int pi = poses_idx[i];
    int qi = patch_idx[i];
    const float* p = poses + (size_t)pi * 7;
    float tx = p[0], ty = p[1], tz = p[2];
    float qx = p[3], qy = p[4], qz = p[5], qw = p[6];
    float inv = rsqrtf(qx*qx + qy*qy + qz*qz + qw*qw);
    qx *= inv; qy *= inv; qz *= inv; qw *= inv;
    float2 pc = *reinterpret_cast<const float2*>(patch_coords + (size_t)qi * 2);
    float px = pc.x, py = pc.y, pz = elev[qi];
    float ux = qy*pz - qz*py, uy = qz*px - qx*pz, uz = qx*py - qy*px;
    float cx = qy*uz - qz*uy, cy = qz*ux - qx*uz, cz = qx*uy - qy*ux;
    float rx = px + 2.0f*(qw*ux + cx) + tx;
    float ry = py + 2.0f*(qw*uy + cy) + ty;
    float rz = pz + 2.0f*(qw*uz + cz) + tz;
    float rho = sqrtf(rx*rx + ry*ry);
    float r   = sqrtf(rho*rho + rz*rz);
    float az  = atan2f(ry, rx);
    float el  = atan2f(rz, rho);
    float w = weights[i];
    out[(size_t)i*3+0] = (r  - target[(size_t)i*3+0]) * w;
    out[(size_t)i*3+1] = (az - target[(size_t)i*3+1]) * w;
    out[(size_t)i*3+2] = (el - target[(size_t)i*3+2]) * w;
}

extern "C" void kernel_launch(void* const* d_in, const int* in_sizes, int n_in,
                              void* d_out, int out_size, void* d_ws, size_t ws_size,
                              hipStream_t stream) {
    const float* poses        = (const float*)d_in[0];
    const float* patch_coords = (const float*)d_in[1];
    const float* elev         = (const float*)d_in[2];
    const int*   poses_idx    = (const int*)d_in[3];
    const int*   patch_idx    = (const int*)d_in[4];
    const float* target       = (const float*)d_in[5];
    const float* weights      = (const float*)d_in[6];
    float*       out          = (float*)d_out;

    int n  = in_sizes[3];  // NUM_OBS (2097152, divisible by 8)
    int n8 = n / 8;

    size_t patch_bytes = (size_t)NPATCHES * 16;              // 4 MiB
    size_t pose_bytes  = (size_t)POSE_LDS_FLOATS * 4;        // 144 KiB

    if (ws_size >= patch_bytes + pose_bytes) {
        fvec4* patch4 = (fvec4*)d_ws;
        float* pose9  = (float*)((char*)d_ws + patch_bytes);

        pack_tables_kernel<<<(NPATCHES + 255) / 256, 256, 0, stream>>>(
            poses, patch_coords, elev, pose9, patch4, NPATCHES);

        int block = 1024;
        int grid  = (n8 + block - 1) / block;  // 256 = one block per CU
        ba_main_kernel<<<grid, block, 0, stream>>>(
            pose9, patch4, poses_idx, patch_idx, target, weights, out, n8);
    } else {
        ba_fallback_kernel<<<(n + 255) / 256, 256, 0, stream>>>(
            poses, patch_coords, elev, poses_idx, patch_idx, target, weights, out, n);
    }
}